// Round 6
// baseline (199.376 us; speedup 1.0000x reference)
//
#include <hip/hip_runtime.h>
#include <math.h>

#define TWO_H 4096
#define HALF_H 2048
#define NGROUPS 8
#define BLOCK 256
#define WPB 4      // waves per block
#define GRID 2048  // 8192 waves; 4 rows per wave at N=32768

typedef int   vi4 __attribute__((ext_vector_type(4)));
typedef float vf4 __attribute__((ext_vector_type(4)));

// One WAVE per row (64 lanes x 32 cols). No barriers anywhere.
// Row buffer o[2048] lives in wave-private LDS (frees ~32 VGPR -> occupancy).
__global__ __launch_bounds__(BLOCK, 4) void swiglu_requant_kernel(
    const int* __restrict__ x,         // [N, 4096] int32
    const float* __restrict__ wscale,  // [G, 4096]
    const float* __restrict__ ascale,  // [N]
    const float* __restrict__ bias,    // [4096]
    const float* __restrict__ qscale,  // [G]
    const int* __restrict__ gindex,    // [G]
    int* __restrict__ out,             // [N, 2048] int32 (int8 values widened)
    int n_rows)
{
    __shared__ float olds[WPB][HALF_H];   // 32 KiB: 8 KiB per wave, private

    const int lane  = threadIdx.x & 63;
    const int wslot = threadIdx.x >> 6;
    float* my_o = &olds[wslot][0];

    const int wid    = blockIdx.x * WPB + wslot;
    const int nwaves = GRID * WPB;

    // bank-deswizzle term: XOR float-index bits 2..3 (keeps 16B alignment,
    // bijective within each 16-float span; identical on write and read)
    const int swz = (lane & 12);   // ((lane>>2)&3)<<2

    // group boundaries (cumsum), wave-uniform in registers
    int cum[NGROUPS];
    {
        int c = 0;
#pragma unroll
        for (int g = 0; g < NGROUPS; ++g) { c += gindex[g]; cum[g] = c; }
    }

    for (int row = wid; row < n_rows; row += nwaves) {
        int gid = 0;
#pragma unroll
        for (int g = 0; g < NGROUPS; ++g) gid += (row >= cum[g]) ? 1 : 0;

        const float a_s = ascale[row];
        const float q_s = qscale[gid];

        const int*   xrow = x + (long)row * TWO_H;
        const float* wrow = wscale + (long)gid * TWO_H;

        float lmax = 0.0f;

#pragma unroll
        for (int c = 0; c < 4; ++c) {
            const int cg = c * 512 + lane * 8;   // gate col start for this chunk

            vi4 g0 = *(const vi4*)(xrow + cg);
            vi4 g1 = *(const vi4*)(xrow + cg + 4);
            vi4 u0 = *(const vi4*)(xrow + HALF_H + cg);
            vi4 u1 = *(const vi4*)(xrow + HALF_H + cg + 4);

            vf4 wg0 = *(const vf4*)(wrow + cg);
            vf4 wg1 = *(const vf4*)(wrow + cg + 4);
            vf4 wu0 = *(const vf4*)(wrow + HALF_H + cg);
            vf4 wu1 = *(const vf4*)(wrow + HALF_H + cg + 4);

            vf4 bg0 = *(const vf4*)(bias + cg);
            vf4 bg1 = *(const vf4*)(bias + cg + 4);
            vf4 bu0 = *(const vf4*)(bias + HALF_H + cg);
            vf4 bu1 = *(const vf4*)(bias + HALF_H + cg + 4);

            float gi[8] = {(float)g0.x, (float)g0.y, (float)g0.z, (float)g0.w,
                           (float)g1.x, (float)g1.y, (float)g1.z, (float)g1.w};
            float ui[8] = {(float)u0.x, (float)u0.y, (float)u0.z, (float)u0.w,
                           (float)u1.x, (float)u1.y, (float)u1.z, (float)u1.w};
            float wgx[8] = {wg0.x, wg0.y, wg0.z, wg0.w, wg1.x, wg1.y, wg1.z, wg1.w};
            float wux[8] = {wu0.x, wu0.y, wu0.z, wu0.w, wu1.x, wu1.y, wu1.z, wu1.w};
            float bgx[8] = {bg0.x, bg0.y, bg0.z, bg0.w, bg1.x, bg1.y, bg1.z, bg1.w};
            float bux[8] = {bu0.x, bu0.y, bu0.z, bu0.w, bu1.x, bu1.y, bu1.z, bu1.w};

            float ov[8];
#pragma unroll
            for (int i = 0; i < 8; ++i) {
                float gv = (gi[i] + bgx[i]) * wgx[i] * a_s;
                float uv = (ui[i] + bux[i]) * wux[i] * a_s;
                float e  = __expf(-uv);
                float sv = uv * __builtin_amdgcn_rcpf(1.0f + e);  // silu(up)
                float o  = sv * gv * q_s;
                ov[i] = o;
                lmax = fmaxf(lmax, fabsf(o));
            }

            // park row values in wave-private LDS (frees registers)
            vf4 o0 = {ov[0], ov[1], ov[2], ov[3]};
            vf4 o1 = {ov[4], ov[5], ov[6], ov[7]};
            *(vf4*)&my_o[(cg    ) ^ swz] = o0;
            *(vf4*)&my_o[(cg + 4) ^ swz] = o1;
        }

        // 64-lane max reduce, registers only — no block barrier anywhere
#pragma unroll
        for (int m = 1; m < 64; m <<= 1)
            lmax = fmaxf(lmax, __shfl_xor(lmax, m, 64));

        const float scale = 127.0f / lmax;

        int* orow = out + (long)row * HALF_H;
#pragma unroll
        for (int c = 0; c < 4; ++c) {
            const int co = c * 512 + lane * 8;
            vf4 o0 = *(const vf4*)&my_o[(co    ) ^ swz];
            vf4 o1 = *(const vf4*)&my_o[(co + 4) ^ swz];
            float ov[8] = {o0.x, o0.y, o0.z, o0.w, o1.x, o1.y, o1.z, o1.w};
            int w[8];
#pragma unroll
            for (int i = 0; i < 8; ++i) {
                float v = ov[i] * scale;
                v = fminf(fmaxf(v, -128.0f), 127.0f);  // clip then round (matches ref)
                w[i] = (int)rintf(v);                   // round half-to-even
            }
            vi4 w0 = {w[0], w[1], w[2], w[3]};
            vi4 w1 = {w[4], w[5], w[6], w[7]};
            *(vi4*)(orow + co)     = w0;
            *(vi4*)(orow + co + 4) = w1;
        }
    }
}

extern "C" void kernel_launch(void* const* d_in, const int* in_sizes, int n_in,
                              void* d_out, int out_size, void* d_ws, size_t ws_size,
                              hipStream_t stream) {
    const int*   x      = (const int*)d_in[0];
    const float* wscale = (const float*)d_in[1];
    const float* ascale = (const float*)d_in[2];
    const float* bias   = (const float*)d_in[3];
    const float* qscale = (const float*)d_in[4];
    const int*   gindex = (const int*)d_in[5];
    int* out = (int*)d_out;

    const int n_rows = in_sizes[0] / TWO_H;  // 32768

    swiglu_requant_kernel<<<GRID, BLOCK, 0, stream>>>(
        x, wscale, ascale, bias, qscale, gindex, out, n_rows);
}